// Round 8
// baseline (109.406 us; speedup 1.0000x reference)
//
#include <hip/hip_runtime.h>
#include <math.h>
#include <string.h>

#define HH 2048
#define WW 2048
#define TSC 128                 // tile cols
#define TSR 32                  // tile rows
#define NBX (WW / TSC)          // 16
#define NBY (HH / TSR)          // 64
#define NTILES (NBX * NBY)      // 1024
#define NINT ((NBX - 2) * (NBY - 2))   // 868 interior tiles

struct Wts { float w[17][5]; float knorm; };

// angle index a: 0 -> -10deg, 1 -> 0deg, 2 -> +10deg
__host__ __device__ constexpr int js_fn(int a, int i) {
  return (a == 1) ? 2
       : (a == 2) ? ((i < 3) ? 0 : (i < 9) ? 1 : (i < 14) ? 2 : 3)
                  : ((i < 3) ? 3 : (i < 8) ? 2 : (i < 14) ? 1 : 0);
}
__host__ __device__ constexpr int nt_fn(int a, int i) {
  return (a == 1) ? 1 : (i == 8) ? 3 : 2;
}

__device__ __forceinline__ float fastrcp(float x) {
#if __has_builtin(__builtin_amdgcn_rcpf)
  return __builtin_amdgcn_rcpf(x);
#else
  return 1.0f / x;
#endif
}

// D0 = Y - X, pure streaming (measured-best kernel shape on this chip)
__global__ __launch_bounds__(256)
void diff_kernel(const float* __restrict__ X, const float* __restrict__ Y,
                 float* __restrict__ D, int n4)
{
  const int stride = gridDim.x * 256;
  for (int i = blockIdx.x * 256 + threadIdx.x; i < n4; i += stride) {
    const float4 x = ((const float4*)X)[i];
    const float4 y = ((const float4*)Y)[i];
    ((float4*)D)[i] = make_float4(y.x - x.x, y.y - x.y, y.z - x.z, y.w - x.w);
  }
}

// Difference-space conv pass, weights pre-divided by knorm = sum(k).
// Single-plane staging (the measured-clean path; no dual-plane fusion):
//  MODE 1: P0=D.       LDS = D.   Out = cen - acc            (= D_next)
//  MODE 2: P0=D, P1=Y. LDS = D.   Out = Ycen - cen + acc     (= X3)
// Interior tiles: no bounds checks, no N read (N == knorm there).
// Boundary tiles: checked staging, acc*knorm/N(pixel).
template <int ANGLE, int DENSE, int MODE>
__global__ __launch_bounds__(256, 3)   // r5/r7-proven: no VGPR squeeze
void conv_iter(const float* __restrict__ P0, const float* __restrict__ P1,
               const float* __restrict__ Nrm, float* __restrict__ Out, Wts wts)
{
  constexpr bool WIN8 = (DENSE || ANGLE != 1);  // angle 0 = single-column kernel
  constexpr int  LSTR = WIN8 ? 148 : 132;       // LDS row stride (floats, skewed)
  constexpr int  LCW  = WIN8 ? 36  : 32;        // staged float4 chunks per row
  constexpr int  XOFF = WIN8 ? 8   : 0;         // left halo cols staged
  constexpr int  CH   = 48 * LCW;               // total chunks: 1728 / 1536
  __shared__ float lds[48 * 148];               // 28416 B

  // chunked XCD swizzle (gridDim.x = 1024*B, divisible by 8): each XCD gets a
  // contiguous band; interior decode is by-fastest so vertical-halo L2 hits.
  const int bid = blockIdx.x;
  const int wg  = (bid & 7) * (gridDim.x >> 3) + (bid >> 3);
  const int bz  = wg >> 10;                     // NTILES == 1024
  const int t0  = wg & 1023;
  int bx, by; bool interior;
  if (t0 < NINT) {
    interior = true;
    bx = 1 + t0 / (NBY - 2);
    by = 1 + t0 % (NBY - 2);
  } else {
    interior = false;
    const int u = t0 - NINT;
    if (u < NBX)          { bx = u;        by = 0; }
    else if (u < 2 * NBX) { bx = u - NBX;  by = NBY - 1; }
    else { const int v = u - 2 * NBX; by = 1 + (v >> 1); bx = (v & 1) ? NBX - 1 : 0; }
  }

  const int tid = threadIdx.x;
  const int x0  = bx * TSC;
  const int y0  = by * TSR;
  const size_t img = (size_t)bz * ((size_t)HH * WW);
  const float* A  = P0 + img;
  const float* Bp = (MODE == 2) ? P1 + img : nullptr;

  // ---- stage 48 x (144|128) window of D into LDS (single plane) ----
  if (interior) {
#pragma unroll
    for (int s = 0; s < (CH + 255) / 256; ++s) {
      const int idx = s * 256 + tid;
      if ((CH % 256 == 0) || idx < CH) {
        const int r  = idx / LCW;
        const int c4 = idx - r * LCW;
        const int gy = y0 - 8 + r;
        const int gx = x0 - XOFF + c4 * 4;
        const float4 v = *(const float4*)(A + (size_t)gy * WW + gx);
        *(float4*)(&lds[r * LSTR + c4 * 4]) = v;
      }
    }
  } else {
#pragma unroll
    for (int s = 0; s < (CH + 255) / 256; ++s) {
      const int idx = s * 256 + tid;
      if ((CH % 256 == 0) || idx < CH) {
        const int r  = idx / LCW;
        const int c4 = idx - r * LCW;
        const int gy = y0 - 8 + r;
        const int gx = x0 - XOFF + c4 * 4;
        float4 v = make_float4(0.f, 0.f, 0.f, 0.f);
        if (gy >= 0 && gy < HH) {
          const float* ar = A + (size_t)gy * WW;
          if (gx >= 0 && gx + 4 <= WW) {
            v = *(const float4*)(ar + gx);
          } else {
            float tv[4] = {0.f, 0.f, 0.f, 0.f};
#pragma unroll
            for (int e = 0; e < 4; ++e) {
              const int gxe = gx + e;
              if (gxe >= 0 && gxe < WW) tv[e] = ar[gxe];
            }
            v = make_float4(tv[0], tv[1], tv[2], tv[3]);
          }
        }
        *(float4*)(&lds[r * LSTR + c4 * 4]) = v;
      }
    }
  }
  __syncthreads();

  // ---- convolution from LDS: thread = 4 cols x 4 rows, diagonal reuse ----
  const int tc = tid & 31;                       // col-group 0..31
  const int tg = tid >> 5;                       // row-group 0..7 (4 rows each)
  const int lc = tc * 4;

  float acc[4][4];
#pragma unroll
  for (int t = 0; t < 4; ++t)
#pragma unroll
    for (int c = 0; c < 4; ++c) acc[t][c] = 0.0f;

#pragma unroll
  for (int rr = 0; rr < 20; ++rr) {
    const int lrow = tg * 4 + rr;
    const float* lp = &lds[lrow * LSTR];
    float win[WIN8 ? 8 : 4];
    if (WIN8) {
      // three aligned b128 reads at 16B lane stride: bank-conflict-free
      const float4 w0 = *(const float4*)(lp + 4 + lc);   // use .z .w
      const float4 w1 = *(const float4*)(lp + 8 + lc);
      const float4 w2 = *(const float4*)(lp + 12 + lc);  // use .x .y
      win[0] = w0.z;  win[1] = w0.w;
      win[2] = w1.x;  win[3] = w1.y;  win[4] = w1.z;  win[5] = w1.w;
      win[6] = w2.x;  win[7] = w2.y;
    } else {
      const float4 w1 = *(const float4*)(lp + lc);
      win[0] = w1.x;  win[1] = w1.y;  win[2] = w1.z;  win[3] = w1.w;
    }
#pragma unroll
    for (int t = 0; t < 4; ++t) {
      const int i = rr - t;                      // compile-time after unroll
      if (i >= 0 && i <= 16) {
        const int js = DENSE ? 0 : js_fn(ANGLE, i);
        const int nt = DENSE ? 5 : nt_fn(ANGLE, i);
#pragma unroll
        for (int jj = 0; jj < nt; ++jj) {
          const float wv = wts.w[i][js + jj];    // kernarg -> SGPR
#pragma unroll
          for (int c = 0; c < 4; ++c)
            acc[t][c] = fmaf(wv, win[(WIN8 ? 0 : -2) + c + js + jj], acc[t][c]);
        }
      }
    }
  }

  // ---- epilogue: cen from LDS; boundary renormalizes by knorm/N ----
  float* Ob = Out + img;
  const int gx = x0 + lc;
  const float kn = wts.knorm;
#pragma unroll
  for (int t = 0; t < 4; ++t) {
    const int yo = y0 + tg * 4 + t;
    const float4 cv = *(const float4*)(&lds[(tg * 4 + t + 8) * LSTR + XOFF + lc]);
    float a0 = acc[t][0], a1 = acc[t][1], a2 = acc[t][2], a3 = acc[t][3];
    if (!interior) {
      const float4 nv = *(const float4*)(Nrm + (size_t)yo * WW + gx);
      a0 = a0 * kn * fastrcp(nv.x);
      a1 = a1 * kn * fastrcp(nv.y);
      a2 = a2 * kn * fastrcp(nv.z);
      a3 = a3 * kn * fastrcp(nv.w);
    }
    float4 o;
    if (MODE == 2) {
      const float4 yv = *(const float4*)(Bp + (size_t)yo * WW + gx);
      o.x = yv.x - cv.x + a0;
      o.y = yv.y - cv.y + a1;
      o.z = yv.z - cv.z + a2;
      o.w = yv.w - cv.w + a3;
    } else {
      o.x = cv.x - a0;
      o.y = cv.y - a1;
      o.z = cv.z - a2;
      o.w = cv.w - a3;
    }
    *(float4*)(Ob + (size_t)yo * WW + gx) = o;
  }
}

// ---------------- host-side replication of _build_kernels ----------------

static void rotate33(const double* src, double* dst, double ang_deg) {
  const int n = 33;
  const double t = ang_deg * 3.14159265358979323846 / 180.0;
  const double cs = cos(t), sn = sin(t);
  for (int y = 0; y < n; ++y) {
    for (int x = 0; x < n; ++x) {
      const double y0 = y - 16.0, x0 = x - 16.0;
      const double sy = cs * y0 + sn * x0 + 16.0;
      const double sx = -sn * y0 + cs * x0 + 16.0;
      const double fy = floor(sy), fx = floor(sx);
      const int y0i = (int)fy, x0i = (int)fx;
      const double wy = sy - fy, wx = sx - fx;
      double o = 0.0;
      for (int dy = 0; dy < 2; ++dy)
        for (int dx = 0; dx < 2; ++dx) {
          const int yy = y0i + dy, xx = x0i + dx;
          if (yy < 0 || yy >= n || xx < 0 || xx >= n) continue;
          const double wgt = (dy ? wy : 1.0 - wy) * (dx ? wx : 1.0 - wx);
          o += wgt * src[yy * n + xx];
        }
      dst[y * n + x] = o;
    }
  }
}

static void build_K(float K[3][17][5]) {
  const double angs[3] = {-10.0, 0.0, 10.0};
  double base[33 * 33], rot[33 * 33];
  for (int i = 0; i < 33 * 33; ++i) base[i] = 0.0;
  for (int y = 0; y < 33; ++y) base[y * 33 + 16] = 1.0;  // ry==0 path
  for (int a = 0; a < 3; ++a) {
    if (a == 1) memcpy(rot, base, sizeof(rot));          // angle % 360 == 0
    else        rotate33(base, rot, angs[a]);
    double k17[17][17];
    for (int y = 0; y < 17; ++y)
      for (int x = 0; x < 17; ++x) k17[y][x] = rot[(y + 8) * 33 + (x + 8)];
    int r = 0, c = 0;
    for (int y = 0; y < 17; ++y) { bool nz = false; for (int x = 0; x < 17; ++x) if (k17[y][x] != 0.0) nz = true; r += nz; }
    for (int x = 0; x < 17; ++x) { bool nz = false; for (int y = 0; y < 17; ++y) if (k17[y][x] != 0.0) nz = true; c += nz; }
    r = r / 2 * 2; c = c / 2 * 2;
    const int kh = r + 1, kw = c + 1;
    for (int y = 0; y < 17; ++y)
      for (int x = 0; x < 5; ++x) K[a][y][x] = 0.0f;
    if (kh <= 17 && kw <= 5) {
      const int oh = (17 - kh) / 2, ow = (5 - kw) / 2;
      for (int y = 0; y < kh; ++y)
        for (int x = 0; x < kw; ++x)
          K[a][oh + y][ow + x] = (float)k17[8 - r / 2 + y][8 - c / 2 + x];
    }
  }
}

// 0 = structured (constexpr jstart/ntaps hold), 1 = dense 5-tap fallback
static int pick_mode(int a, const float K[17][5]) {
  for (int i = 0; i < 17; ++i) {
    const int js = js_fn(a, i), nt = nt_fn(a, i);
    for (int j = 0; j < 5; ++j)
      if ((j < js || j >= js + nt) && K[i][j] != 0.0f) return 1;
  }
  return 0;
}

template <int A, int MODE>
static void launch_iter(int dense, const float* P0, const float* P1, const float* Nrm,
                        float* Out, const Wts& w, int B, hipStream_t s) {
  dim3 grid(NTILES * B), blk(256);
  if (dense == 0) conv_iter<A, 0, MODE><<<grid, blk, 0, s>>>(P0, P1, Nrm, Out, w);
  else            conv_iter<A, 1, MODE><<<grid, blk, 0, s>>>(P0, P1, Nrm, Out, w);
}

extern "C" void kernel_launch(void* const* d_in, const int* in_sizes, int n_in,
                              void* d_out, int out_size, void* d_ws, size_t ws_size,
                              hipStream_t stream) {
  const float* X  = (const float*)d_in[0];
  const float* Y  = (const float*)d_in[1];
  const float* Nn = (const float*)d_in[3];
  float* out = (float*)d_out;
  float* tmp = (float*)d_ws;   // needs B*H*W*4 = 33.6 MB of scratch
  const size_t HW = (size_t)HH * WW;
  const int B = in_sizes[0] / (int)HW;   // 2

  float K[3][17][5];
  build_K(K);
  Wts w[3];
  for (int a = 0; a < 3; ++a) {
    double ks = 0.0;
    for (int i = 0; i < 17; ++i)
      for (int j = 0; j < 5; ++j) ks += K[a][i][j];
    const float kn = (float)ks;
    for (int i = 0; i < 17; ++i)
      for (int j = 0; j < 5; ++j) w[a].w[i][j] = K[a][i][j] / kn;
    w[a].knorm = kn;
  }
  const int m0 = pick_mode(0, K[0]);
  const int m1 = pick_mode(1, K[1]);
  const int m2 = pick_mode(2, K[2]);

  // D0 = Y - X (streaming), then three single-plane conv passes:
  //   D0 -> tmp; conv0: tmp -> out (D1); conv1: out -> tmp (D2, D0 dead);
  //   conv2: tmp (+Y epilogue) -> out (X3).
  const int n4 = (int)(B * HW / 4);
  diff_kernel<<<dim3(2048), dim3(256), 0, stream>>>(X, Y, tmp, n4);
  launch_iter<0, 1>(m0, tmp, nullptr, Nn,          out, w[0], B, stream);  // D1
  launch_iter<1, 1>(m1, out, nullptr, Nn + HW,     tmp, w[1], B, stream);  // D2
  launch_iter<2, 2>(m2, tmp, Y,       Nn + 2 * HW, out, w[2], B, stream);  // X3
}

// Round 9
// 95.187 us; speedup vs baseline: 1.1494x; 1.1494x over previous
//
#include <hip/hip_runtime.h>
#include <math.h>
#include <string.h>

#define HH 2048
#define WW 2048
#define TSC 128                 // tile cols
#define TSR 32                  // tile rows
#define NBX (WW / TSC)          // 16
#define NBY (HH / TSR)          // 64
#define NINT1 ((NBX - 2) * (NBY - 2))  // 868 interior tiles per image
#define NBND1 (NBX * NBY - NINT1)      // 156 boundary tiles per image

struct Wts { float w[17][5]; float knorm; };

// angle index a: 0 -> -10deg, 1 -> 0deg, 2 -> +10deg
__host__ __device__ constexpr int js_fn(int a, int i) {
  return (a == 1) ? 2
       : (a == 2) ? ((i < 3) ? 0 : (i < 9) ? 1 : (i < 14) ? 2 : 3)
                  : ((i < 3) ? 3 : (i < 8) ? 2 : (i < 14) ? 1 : 0);
}
__host__ __device__ constexpr int nt_fn(int a, int i) {
  return (a == 1) ? 1 : (i == 8) ? 3 : 2;
}

__device__ __forceinline__ float fastrcp(float x) {
#if __has_builtin(__builtin_amdgcn_rcpf)
  return __builtin_amdgcn_rcpf(x);
#else
  return 1.0f / x;
#endif
}

// D0 = Y - X, pure streaming
__global__ __launch_bounds__(256)
void diff_kernel(const float* __restrict__ X, const float* __restrict__ Y,
                 float* __restrict__ D, int n4)
{
  const int stride = gridDim.x * 256;
  for (int i = blockIdx.x * 256 + threadIdx.x; i < n4; i += stride) {
    const float4 x = ((const float4*)X)[i];
    const float4 y = ((const float4*)Y)[i];
    ((float4*)D)[i] = make_float4(y.x - x.x, y.y - x.y, y.z - x.z, y.w - x.w);
  }
}

// ======================= INTERIOR kernel (single path) =======================
// Weights pre-divided by knorm; N == knorm on all interior pixels -> no N read,
// no bounds checks anywhere. MODE 1: Out = cen - acc. MODE 2: Out = Ycen-cen+acc.
template <int ANGLE, int DENSE, int MODE>
__global__ __launch_bounds__(256, 3)
void conv_int(const float* __restrict__ P0, const float* __restrict__ P1,
              float* __restrict__ Out, Wts wts)
{
  constexpr bool WIN8 = (DENSE || ANGLE != 1);
  constexpr int  LSTR = WIN8 ? 148 : 132;
  constexpr int  LCW  = WIN8 ? 36  : 32;
  constexpr int  XOFF = WIN8 ? 8   : 0;
  constexpr int  CH   = 48 * LCW;
  __shared__ float lds[48 * 148];

  // chunked XCD swizzle (identity if grid not divisible by 8)
  const int bid = blockIdx.x, nwg = gridDim.x;
  const int wg  = ((nwg & 7) == 0) ? ((bid & 7) * (nwg >> 3) + (bid >> 3)) : bid;
  const int bz  = wg / NINT1;
  const int t0  = wg - bz * NINT1;
  const int bx  = 1 + t0 / (NBY - 2);
  const int by  = 1 + t0 % (NBY - 2);     // by-fastest: vertical-halo L2 hits

  const int tid = threadIdx.x;
  const int x0  = bx * TSC;
  const int y0  = by * TSR;
  const size_t img = (size_t)bz * ((size_t)HH * WW);
  const float* A  = P0 + img;

  // ---- stage 48 x (144|128) window of D into LDS (unchecked) ----
#pragma unroll
  for (int s = 0; s < (CH + 255) / 256; ++s) {
    const int idx = s * 256 + tid;
    if ((CH % 256 == 0) || idx < CH) {
      const int r  = idx / LCW;
      const int c4 = idx - r * LCW;
      const float4 v = *(const float4*)(A + (size_t)(y0 - 8 + r) * WW + (x0 - XOFF + c4 * 4));
      *(float4*)(&lds[r * LSTR + c4 * 4]) = v;
    }
  }
  __syncthreads();

  // ---- convolution from LDS: thread = 4 cols x 4 rows, diagonal reuse ----
  const int tc = tid & 31;
  const int tg = tid >> 5;
  const int lc = tc * 4;

  float acc[4][4];
#pragma unroll
  for (int t = 0; t < 4; ++t)
#pragma unroll
    for (int c = 0; c < 4; ++c) acc[t][c] = 0.0f;

#pragma unroll
  for (int rr = 0; rr < 20; ++rr) {
    const float* lp = &lds[(tg * 4 + rr) * LSTR];
    float win[WIN8 ? 8 : 4];
    if (WIN8) {
      const float4 w0 = *(const float4*)(lp + 4 + lc);
      const float4 w1 = *(const float4*)(lp + 8 + lc);
      const float4 w2 = *(const float4*)(lp + 12 + lc);
      win[0] = w0.z;  win[1] = w0.w;
      win[2] = w1.x;  win[3] = w1.y;  win[4] = w1.z;  win[5] = w1.w;
      win[6] = w2.x;  win[7] = w2.y;
    } else {
      const float4 w1 = *(const float4*)(lp + lc);
      win[0] = w1.x;  win[1] = w1.y;  win[2] = w1.z;  win[3] = w1.w;
    }
#pragma unroll
    for (int t = 0; t < 4; ++t) {
      const int i = rr - t;
      if (i >= 0 && i <= 16) {
        const int js = DENSE ? 0 : js_fn(ANGLE, i);
        const int nt = DENSE ? 5 : nt_fn(ANGLE, i);
#pragma unroll
        for (int jj = 0; jj < nt; ++jj) {
          const float wv = wts.w[i][js + jj];
#pragma unroll
          for (int c = 0; c < 4; ++c)
            acc[t][c] = fmaf(wv, win[(WIN8 ? 0 : -2) + c + js + jj], acc[t][c]);
        }
      }
    }
  }

  // ---- epilogue (no N, no bounds) ----
  float* Ob = Out + img;
  const int gx = x0 + lc;
#pragma unroll
  for (int t = 0; t < 4; ++t) {
    const int yo = y0 + tg * 4 + t;
    const float4 cv = *(const float4*)(&lds[(tg * 4 + t + 8) * LSTR + XOFF + lc]);
    float4 o;
    if (MODE == 2) {
      const float4 yv = *(const float4*)(P1 + img + (size_t)yo * WW + gx);
      o.x = yv.x - cv.x + acc[t][0];
      o.y = yv.y - cv.y + acc[t][1];
      o.z = yv.z - cv.z + acc[t][2];
      o.w = yv.w - cv.w + acc[t][3];
    } else {
      o.x = cv.x - acc[t][0];
      o.y = cv.y - acc[t][1];
      o.z = cv.z - acc[t][2];
      o.w = cv.w - acc[t][3];
    }
    *(float4*)(Ob + (size_t)yo * WW + gx) = o;
  }
}

// ======================= BOUNDARY kernel (checked path) ======================
template <int ANGLE, int DENSE, int MODE>
__global__ __launch_bounds__(256, 3)
void conv_bnd(const float* __restrict__ P0, const float* __restrict__ P1,
              const float* __restrict__ Nrm, float* __restrict__ Out, Wts wts)
{
  constexpr bool WIN8 = (DENSE || ANGLE != 1);
  constexpr int  LSTR = WIN8 ? 148 : 132;
  constexpr int  LCW  = WIN8 ? 36  : 32;
  constexpr int  XOFF = WIN8 ? 8   : 0;
  constexpr int  CH   = 48 * LCW;
  __shared__ float lds[48 * 148];

  const int u = blockIdx.x;
  int bx, by;
  if (u < NBX)          { bx = u;        by = 0; }
  else if (u < 2 * NBX) { bx = u - NBX;  by = NBY - 1; }
  else { const int v = u - 2 * NBX; by = 1 + (v >> 1); bx = (v & 1) ? NBX - 1 : 0; }
  const int bz = blockIdx.y;

  const int tid = threadIdx.x;
  const int x0  = bx * TSC;
  const int y0  = by * TSR;
  const size_t img = (size_t)bz * ((size_t)HH * WW);
  const float* A  = P0 + img;

  // ---- checked staging, zero-filled OOB ----
#pragma unroll
  for (int s = 0; s < (CH + 255) / 256; ++s) {
    const int idx = s * 256 + tid;
    if ((CH % 256 == 0) || idx < CH) {
      const int r  = idx / LCW;
      const int c4 = idx - r * LCW;
      const int gy = y0 - 8 + r;
      const int gx = x0 - XOFF + c4 * 4;
      float4 v = make_float4(0.f, 0.f, 0.f, 0.f);
      if (gy >= 0 && gy < HH) {
        const float* ar = A + (size_t)gy * WW;
        if (gx >= 0 && gx + 4 <= WW) {
          v = *(const float4*)(ar + gx);
        } else {
          float tv[4] = {0.f, 0.f, 0.f, 0.f};
#pragma unroll
          for (int e = 0; e < 4; ++e) {
            const int gxe = gx + e;
            if (gxe >= 0 && gxe < WW) tv[e] = ar[gxe];
          }
          v = make_float4(tv[0], tv[1], tv[2], tv[3]);
        }
      }
      *(float4*)(&lds[r * LSTR + c4 * 4]) = v;
    }
  }
  __syncthreads();

  const int tc = tid & 31;
  const int tg = tid >> 5;
  const int lc = tc * 4;

  float acc[4][4];
#pragma unroll
  for (int t = 0; t < 4; ++t)
#pragma unroll
    for (int c = 0; c < 4; ++c) acc[t][c] = 0.0f;

#pragma unroll
  for (int rr = 0; rr < 20; ++rr) {
    const float* lp = &lds[(tg * 4 + rr) * LSTR];
    float win[WIN8 ? 8 : 4];
    if (WIN8) {
      const float4 w0 = *(const float4*)(lp + 4 + lc);
      const float4 w1 = *(const float4*)(lp + 8 + lc);
      const float4 w2 = *(const float4*)(lp + 12 + lc);
      win[0] = w0.z;  win[1] = w0.w;
      win[2] = w1.x;  win[3] = w1.y;  win[4] = w1.z;  win[5] = w1.w;
      win[6] = w2.x;  win[7] = w2.y;
    } else {
      const float4 w1 = *(const float4*)(lp + lc);
      win[0] = w1.x;  win[1] = w1.y;  win[2] = w1.z;  win[3] = w1.w;
    }
#pragma unroll
    for (int t = 0; t < 4; ++t) {
      const int i = rr - t;
      if (i >= 0 && i <= 16) {
        const int js = DENSE ? 0 : js_fn(ANGLE, i);
        const int nt = DENSE ? 5 : nt_fn(ANGLE, i);
#pragma unroll
        for (int jj = 0; jj < nt; ++jj) {
          const float wv = wts.w[i][js + jj];
#pragma unroll
          for (int c = 0; c < 4; ++c)
            acc[t][c] = fmaf(wv, win[(WIN8 ? 0 : -2) + c + js + jj], acc[t][c]);
        }
      }
    }
  }

  // ---- epilogue with per-pixel renormalization knorm/N ----
  float* Ob = Out + img;
  const int gx = x0 + lc;
  const float kn = wts.knorm;
#pragma unroll
  for (int t = 0; t < 4; ++t) {
    const int yo = y0 + tg * 4 + t;
    const float4 cv = *(const float4*)(&lds[(tg * 4 + t + 8) * LSTR + XOFF + lc]);
    const float4 nv = *(const float4*)(Nrm + (size_t)yo * WW + gx);
    const float a0 = acc[t][0] * kn * fastrcp(nv.x);
    const float a1 = acc[t][1] * kn * fastrcp(nv.y);
    const float a2 = acc[t][2] * kn * fastrcp(nv.z);
    const float a3 = acc[t][3] * kn * fastrcp(nv.w);
    float4 o;
    if (MODE == 2) {
      const float4 yv = *(const float4*)(P1 + img + (size_t)yo * WW + gx);
      o.x = yv.x - cv.x + a0;
      o.y = yv.y - cv.y + a1;
      o.z = yv.z - cv.z + a2;
      o.w = yv.w - cv.w + a3;
    } else {
      o.x = cv.x - a0;
      o.y = cv.y - a1;
      o.z = cv.z - a2;
      o.w = cv.w - a3;
    }
    *(float4*)(Ob + (size_t)yo * WW + gx) = o;
  }
}

// ---------------- host-side replication of _build_kernels ----------------

static void rotate33(const double* src, double* dst, double ang_deg) {
  const int n = 33;
  const double t = ang_deg * 3.14159265358979323846 / 180.0;
  const double cs = cos(t), sn = sin(t);
  for (int y = 0; y < n; ++y) {
    for (int x = 0; x < n; ++x) {
      const double y0 = y - 16.0, x0 = x - 16.0;
      const double sy = cs * y0 + sn * x0 + 16.0;
      const double sx = -sn * y0 + cs * x0 + 16.0;
      const double fy = floor(sy), fx = floor(sx);
      const int y0i = (int)fy, x0i = (int)fx;
      const double wy = sy - fy, wx = sx - fx;
      double o = 0.0;
      for (int dy = 0; dy < 2; ++dy)
        for (int dx = 0; dx < 2; ++dx) {
          const int yy = y0i + dy, xx = x0i + dx;
          if (yy < 0 || yy >= n || xx < 0 || xx >= n) continue;
          const double wgt = (dy ? wy : 1.0 - wy) * (dx ? wx : 1.0 - wx);
          o += wgt * src[yy * n + xx];
        }
      dst[y * n + x] = o;
    }
  }
}

static void build_K(float K[3][17][5]) {
  const double angs[3] = {-10.0, 0.0, 10.0};
  double base[33 * 33], rot[33 * 33];
  for (int i = 0; i < 33 * 33; ++i) base[i] = 0.0;
  for (int y = 0; y < 33; ++y) base[y * 33 + 16] = 1.0;  // ry==0 path
  for (int a = 0; a < 3; ++a) {
    if (a == 1) memcpy(rot, base, sizeof(rot));          // angle % 360 == 0
    else        rotate33(base, rot, angs[a]);
    double k17[17][17];
    for (int y = 0; y < 17; ++y)
      for (int x = 0; x < 17; ++x) k17[y][x] = rot[(y + 8) * 33 + (x + 8)];
    int r = 0, c = 0;
    for (int y = 0; y < 17; ++y) { bool nz = false; for (int x = 0; x < 17; ++x) if (k17[y][x] != 0.0) nz = true; r += nz; }
    for (int x = 0; x < 17; ++x) { bool nz = false; for (int y = 0; y < 17; ++y) if (k17[y][x] != 0.0) nz = true; c += nz; }
    r = r / 2 * 2; c = c / 2 * 2;
    const int kh = r + 1, kw = c + 1;
    for (int y = 0; y < 17; ++y)
      for (int x = 0; x < 5; ++x) K[a][y][x] = 0.0f;
    if (kh <= 17 && kw <= 5) {
      const int oh = (17 - kh) / 2, ow = (5 - kw) / 2;
      for (int y = 0; y < kh; ++y)
        for (int x = 0; x < kw; ++x)
          K[a][oh + y][ow + x] = (float)k17[8 - r / 2 + y][8 - c / 2 + x];
    }
  }
}

// 0 = structured (constexpr jstart/ntaps hold), 1 = dense 5-tap fallback
static int pick_mode(int a, const float K[17][5]) {
  for (int i = 0; i < 17; ++i) {
    const int js = js_fn(a, i), nt = nt_fn(a, i);
    for (int j = 0; j < 5; ++j)
      if ((j < js || j >= js + nt) && K[i][j] != 0.0f) return 1;
  }
  return 0;
}

template <int A, int MODE>
static void launch_iter(int dense, const float* P0, const float* P1, const float* Nrm,
                        float* Out, const Wts& w, int B, hipStream_t s) {
  dim3 gi(NINT1 * B), gb(NBND1, B), blk(256);
  if (dense == 0) {
    conv_int<A, 0, MODE><<<gi, blk, 0, s>>>(P0, P1, Out, w);
    conv_bnd<A, 0, MODE><<<gb, blk, 0, s>>>(P0, P1, Nrm, Out, w);
  } else {
    conv_int<A, 1, MODE><<<gi, blk, 0, s>>>(P0, P1, Out, w);
    conv_bnd<A, 1, MODE><<<gb, blk, 0, s>>>(P0, P1, Nrm, Out, w);
  }
}

extern "C" void kernel_launch(void* const* d_in, const int* in_sizes, int n_in,
                              void* d_out, int out_size, void* d_ws, size_t ws_size,
                              hipStream_t stream) {
  const float* X  = (const float*)d_in[0];
  const float* Y  = (const float*)d_in[1];
  const float* Nn = (const float*)d_in[3];
  float* out = (float*)d_out;
  float* tmp = (float*)d_ws;   // needs B*H*W*4 = 33.6 MB of scratch
  const size_t HW = (size_t)HH * WW;
  const int B = in_sizes[0] / (int)HW;   // 2

  float K[3][17][5];
  build_K(K);
  Wts w[3];
  for (int a = 0; a < 3; ++a) {
    double ks = 0.0;
    for (int i = 0; i < 17; ++i)
      for (int j = 0; j < 5; ++j) ks += K[a][i][j];
    const float kn = (float)ks;
    for (int i = 0; i < 17; ++i)
      for (int j = 0; j < 5; ++j) w[a].w[i][j] = K[a][i][j] / kn;
    w[a].knorm = kn;
  }
  const int m0 = pick_mode(0, K[0]);
  const int m1 = pick_mode(1, K[1]);
  const int m2 = pick_mode(2, K[2]);

  // D0 = Y - X (streaming), then three single-plane conv passes:
  //   D0 -> tmp; conv0: tmp -> out (D1); conv1: out -> tmp (D2);
  //   conv2: tmp (+Y epilogue) -> out (X3).
  const int n4 = (int)(B * HW / 4);
  const int dg = (n4 + 255) / 256;
  diff_kernel<<<dim3(dg > 8192 ? 8192 : dg), dim3(256), 0, stream>>>(X, Y, tmp, n4);
  launch_iter<0, 1>(m0, tmp, nullptr, Nn,          out, w[0], B, stream);  // D1
  launch_iter<1, 1>(m1, out, nullptr, Nn + HW,     tmp, w[1], B, stream);  // D2
  launch_iter<2, 2>(m2, tmp, Y,       Nn + 2 * HW, out, w[2], B, stream);  // X3
}